// Round 1
// baseline (409.493 us; speedup 1.0000x reference)
//
#include <hip/hip_runtime.h>

// SConv: x(8,64,128,128) f32, Coefficient(9,9), W(128,64,3,3), b(128)
// out[b,co,h,w] = sum_{c,t} z[b,c,h,w][t] * W[co,c,t] + b[co]
// where z = [sorted8(y[noncenter]) split 4|4 around raw center x[b,c,h,w]]
// and y_i = sum_j Coefficient[i,j] * patch_j (3x3 neighborhood, zero pad 1).

#define B_   8
#define C_   64
#define H_   128
#define W_   128
#define CO_  128
#define WT   16   // w-tile per block

__device__ __forceinline__ void cswap(float &a, float &b) {
    float lo = fminf(a, b);
    float hi = fmaxf(a, b);
    a = lo; b = hi;
}

// Wt[(c*9+t)*128 + co] = W[(co*64+c)*9 + t]
__global__ __launch_bounds__(256) void transpose_W(const float* __restrict__ Wg,
                                                   float* __restrict__ Wt) {
    int idx = blockIdx.x * 256 + threadIdx.x;
    if (idx >= C_ * 9 * CO_) return;
    int co = idx & 127;
    int ct = idx >> 7;        // c*9 + t
    int c  = ct / 9;
    int t  = ct - c * 9;
    Wt[idx] = Wg[(co * C_ + c) * 9 + t];
}

template <bool TRANSPOSED>
__global__ __launch_bounds__(256) void sconv_fused(
    const float* __restrict__ x,
    const float* __restrict__ Coef,
    const float* __restrict__ Wg,      // transposed [c*9+t][co] if TRANSPOSED, else [co][c][t]
    const float* __restrict__ bias,
    float* __restrict__ out)
{
    __shared__ float Cf[81];
    __shared__ float Zl[C_ * 9 * WT];   // [(c*9+t)*16 + wl]  (36 KB)

    const int tid = threadIdx.x;
    const int bx  = blockIdx.x;
    const int wt  = bx & 7;            // W_/WT = 8 tiles
    const int h   = (bx >> 3) & 127;
    const int b   = bx >> 10;
    const int w0  = wt * WT;

    if (tid < 81) Cf[tid] = Coef[tid];
    __syncthreads();

    // ---- Phase A: build z-vectors for 64 c x 16 w into LDS ----
    for (int task = tid; task < C_ * WT; task += 256) {
        const int c  = task >> 4;
        const int wl = task & 15;
        const int w  = w0 + wl;
        const float* xb = x + (b * C_ + c) * H_ * W_;

        float p[9];
        #pragma unroll
        for (int dy = 0; dy < 3; ++dy) {
            const int hy = h + dy - 1;
            const bool hin = (hy >= 0) && (hy < H_);
            #pragma unroll
            for (int dx = 0; dx < 3; ++dx) {
                const int wx = w + dx - 1;
                const bool win = (wx >= 0) && (wx < W_);
                p[dy * 3 + dx] = (hin && win) ? xb[hy * W_ + wx] : 0.0f;
            }
        }

        // y_i for i in {0,1,2,3,5,6,7,8} (y[4] is discarded by the reference)
        float v[8];
        #pragma unroll
        for (int ii = 0; ii < 8; ++ii) {
            const int i = (ii < 4) ? ii : ii + 1;
            float acc = 0.0f;
            #pragma unroll
            for (int j = 0; j < 9; ++j) acc = fmaf(Cf[i * 9 + j], p[j], acc);
            v[ii] = acc;
        }

        // Batcher odd-even mergesort, 8 elements, ascending (19 comparators)
        cswap(v[0], v[1]); cswap(v[2], v[3]); cswap(v[4], v[5]); cswap(v[6], v[7]);
        cswap(v[0], v[2]); cswap(v[1], v[3]); cswap(v[4], v[6]); cswap(v[5], v[7]);
        cswap(v[1], v[2]); cswap(v[5], v[6]);
        cswap(v[0], v[4]); cswap(v[1], v[5]); cswap(v[2], v[6]); cswap(v[3], v[7]);
        cswap(v[2], v[4]); cswap(v[3], v[5]);
        cswap(v[1], v[2]); cswap(v[3], v[4]); cswap(v[5], v[6]);

        // z (REORDER applied): [s0,s1,s2,s3, center, s4,s5,s6,s7]
        const int base = c * 9 * WT + wl;
        Zl[base + 0 * WT] = v[0];
        Zl[base + 1 * WT] = v[1];
        Zl[base + 2 * WT] = v[2];
        Zl[base + 3 * WT] = v[3];
        Zl[base + 4 * WT] = p[4];
        Zl[base + 5 * WT] = v[4];
        Zl[base + 6 * WT] = v[5];
        Zl[base + 7 * WT] = v[6];
        Zl[base + 8 * WT] = v[7];
    }
    __syncthreads();

    // ---- Phase B: contraction. thread = (co, half of the 16 w's) ----
    const int co  = tid >> 1;
    const int w0l = (tid & 1) * 8;

    float acc[8];
    #pragma unroll
    for (int i = 0; i < 8; ++i) acc[i] = 0.0f;

    for (int c = 0; c < C_; ++c) {
        #pragma unroll
        for (int t = 0; t < 9; ++t) {
            float wv;
            if (TRANSPOSED) wv = Wg[(c * 9 + t) * CO_ + co];
            else            wv = Wg[(co * C_ + c) * 9 + t];
            const float* zp = &Zl[(c * 9 + t) * WT + w0l];
            const float4 za = *(const float4*)zp;
            const float4 zb = *(const float4*)(zp + 4);
            acc[0] = fmaf(za.x, wv, acc[0]);
            acc[1] = fmaf(za.y, wv, acc[1]);
            acc[2] = fmaf(za.z, wv, acc[2]);
            acc[3] = fmaf(za.w, wv, acc[3]);
            acc[4] = fmaf(zb.x, wv, acc[4]);
            acc[5] = fmaf(zb.y, wv, acc[5]);
            acc[6] = fmaf(zb.z, wv, acc[6]);
            acc[7] = fmaf(zb.w, wv, acc[7]);
        }
    }

    const float bv = bias[co];
    float4 o0 = make_float4(acc[0] + bv, acc[1] + bv, acc[2] + bv, acc[3] + bv);
    float4 o1 = make_float4(acc[4] + bv, acc[5] + bv, acc[6] + bv, acc[7] + bv);
    float* op = out + ((b * CO_ + co) * H_ + h) * W_ + w0 + w0l;
    *(float4*)(op)     = o0;
    *(float4*)(op + 4) = o1;
}

extern "C" void kernel_launch(void* const* d_in, const int* in_sizes, int n_in,
                              void* d_out, int out_size, void* d_ws, size_t ws_size,
                              hipStream_t stream) {
    const float* x    = (const float*)d_in[0];
    const float* Coef = (const float*)d_in[1];
    const float* Wg   = (const float*)d_in[2];
    const float* bias = (const float*)d_in[3];
    float* out = (float*)d_out;

    const size_t wt_bytes = (size_t)C_ * 9 * CO_ * sizeof(float);
    const int grid = B_ * H_ * (W_ / WT);   // 8192

    if (ws_size >= wt_bytes) {
        float* Wt = (float*)d_ws;
        transpose_W<<<(C_ * 9 * CO_ + 255) / 256, 256, 0, stream>>>(Wg, Wt);
        sconv_fused<true><<<grid, 256, 0, stream>>>(x, Coef, Wt, bias, out);
    } else {
        sconv_fused<false><<<grid, 256, 0, stream>>>(x, Coef, Wg, bias, out);
    }
}

// Round 5
// 183.719 us; speedup vs baseline: 2.2289x; 2.2289x over previous
//
#include <hip/hip_runtime.h>
#include <hip/hip_bf16.h>

// SConv: x(8,64,128,128) f32, Coefficient(9,9), W(128,64,3,3), b(128)
// out[b,co,h,w] = sum_{c,t} z[b,c,h,w][t] * W[co,c,t] + b[co]
// z = [sorted8(y[noncenter])[0:4], center, sorted8[4:8]],
// y_i = sum_j Coefficient[i,j] * patch_j (3x3 neighborhood, zero pad 1).
//
// Round 5: round-4 design, MFMA operand types hardened. gfx950's
// __builtin_amdgcn_mfma_f32_16x16x32_bf16 signature is V4f(V8y,V8y,V4f,...)
// with y = __bf16; passing short8 relies on lax vector conversions and is the
// prime remaining suspect for the compile/container failures. Fragments are
// now explicit __bf16 ext-vectors via __builtin_bit_cast (zero runtime cost).
// LDS 37 KB/block, 256 threads / 4 waves; each wave: 2 m-tiles x 2 n-tiles.
// Verified layouts (m89/m91/m97): A[m=lane&15][k=(lane>>4)*8+j], B^T rows,
// C/D row=(lane>>4)*4+reg, col=lane&15. Z in LDS [32 m][576 k] bf16 with
// 8-elem chunk XOR swizzle (conflict-free b128 reads).

#define B_   8
#define C_   64
#define H_   128
#define W_   128
#define CO_  128
#define K_   576   // C_*9
#define MT   32    // sites (w) per block

typedef __attribute__((ext_vector_type(8))) short  short8;
typedef __attribute__((ext_vector_type(8))) __bf16 bf16x8;
typedef __attribute__((ext_vector_type(4))) float  f32x4;

__device__ __forceinline__ void cswap(float &a, float &b) {
    float lo = fminf(a, b);
    float hi = fmaxf(a, b);
    a = lo; b = hi;
}

__device__ __forceinline__ ushort f2bf(float f) {
    union { float f; unsigned u; } v; v.f = f;
    unsigned r = v.u + 0x7fffu + ((v.u >> 16) & 1u);  // RNE
    return (ushort)(r >> 16);
}

// W[co][c][t] f32 -> bf16 (layout already B^T = [n=co][k=c*9+t])
__global__ __launch_bounds__(256) void conv_W_bf16(const float* __restrict__ Wg,
                                                   ushort* __restrict__ Wb) {
    int i = blockIdx.x * 256 + threadIdx.x;
    if (i < CO_ * K_) Wb[i] = f2bf(Wg[i]);
}

__global__ __launch_bounds__(256) void sconv_mfma(
    const float* __restrict__ x,
    const float* __restrict__ Coef,
    const ushort* __restrict__ Wb,     // bf16 bits [co][k]
    const float* __restrict__ bias,
    float* __restrict__ out)
{
    __shared__ float  Cf[81];
    __shared__ ushort Zl[MT * K_];     // 36864 B, chunk-swizzled

    const int tid = threadIdx.x;
    const int bx  = blockIdx.x;
    const int wq  = bx & 3;            // which 32-wide quarter of the row
    const int h   = (bx >> 2) & 127;
    const int b   = bx >> 9;
    const int w0  = wq * MT;

    if (tid < 81) Cf[tid] = Coef[tid];
    __syncthreads();

    // ---- Phase A: build z (bf16) for 64 c x 32 sites into swizzled LDS ----
    for (int it = 0; it < 8; ++it) {           // 2048 tasks / 256 threads
        const int task = tid + it * 256;
        const int c = task >> 5;
        const int m = task & 31;
        const int w = w0 + m;
        const float* xb = x + ((size_t)(b * C_ + c)) * (H_ * W_);

        float p[9];
        #pragma unroll
        for (int dy = 0; dy < 3; ++dy) {
            const int hy = h + dy - 1;
            const bool hin = (unsigned)hy < (unsigned)H_;
            #pragma unroll
            for (int dx = 0; dx < 3; ++dx) {
                const int wx = w + dx - 1;
                const bool win = (unsigned)wx < (unsigned)W_;
                p[dy * 3 + dx] = (hin && win) ? xb[hy * W_ + wx] : 0.0f;
            }
        }

        float v[8];
        #pragma unroll
        for (int ii = 0; ii < 8; ++ii) {
            const int i = ii + (ii >> 2);      // 0,1,2,3,5,6,7,8
            float acc = 0.0f;
            #pragma unroll
            for (int j = 0; j < 9; ++j) acc = fmaf(Cf[i * 9 + j], p[j], acc);
            v[ii] = acc;
        }

        // Batcher odd-even mergesort, 8 elems, ascending (19 comparators)
        cswap(v[0], v[1]); cswap(v[2], v[3]); cswap(v[4], v[5]); cswap(v[6], v[7]);
        cswap(v[0], v[2]); cswap(v[1], v[3]); cswap(v[4], v[6]); cswap(v[5], v[7]);
        cswap(v[1], v[2]); cswap(v[5], v[6]);
        cswap(v[0], v[4]); cswap(v[1], v[5]); cswap(v[2], v[6]); cswap(v[3], v[7]);
        cswap(v[2], v[4]); cswap(v[3], v[5]);
        cswap(v[1], v[2]); cswap(v[3], v[4]); cswap(v[5], v[6]);

        float zv[9] = { v[0], v[1], v[2], v[3], p[4], v[4], v[5], v[6], v[7] };

        const int mb = m * K_;
        const int ms = (m & 7) << 3;           // XOR pattern on chunk base
        #pragma unroll
        for (int t = 0; t < 9; ++t) {
            const int k = c * 9 + t;
            const int idx = mb + (((k & ~7) ^ ms) | (k & 7));
            Zl[idx] = f2bf(zv[t]);
        }
    }
    __syncthreads();

    // ---- Phase B: MFMA GEMM  out[m, n=co] = sum_k Z[m,k] * W^T[n,k] ----
    const int wave = tid >> 6;         // 4 waves
    const int lane = tid & 63;
    const int quad = lane >> 4;
    const int l16  = lane & 15;
    const int nt0  = wave * 2;         // n-tiles nt0, nt0+1 (co)

    const int m0 = l16;                // m-tile 0 row
    const int m1 = l16 + 16;           // m-tile 1 row
    const ushort* arow0 = &Zl[m0 * K_];
    const ushort* arow1 = &Zl[m1 * K_];
    const int ms0 = (m0 & 7) << 3;
    const int ms1 = (m1 & 7) << 3;
    const ushort* brow0 = Wb + (size_t)(nt0 * 16 + l16) * K_ + quad * 8;
    const ushort* brow1 = brow0 + (size_t)16 * K_;

    f32x4 acc00 = {0.f,0.f,0.f,0.f}, acc01 = acc00, acc10 = acc00, acc11 = acc00;

    #pragma unroll
    for (int ks = 0; ks < 18; ++ks) {
        const int kq = ks * 32 + quad * 8;     // this lane's k-chunk base
        bf16x8 a0  = __builtin_bit_cast(bf16x8, *(const short8*)(arow0 + (kq ^ ms0)));
        bf16x8 a1  = __builtin_bit_cast(bf16x8, *(const short8*)(arow1 + (kq ^ ms1)));
        bf16x8 bb0 = __builtin_bit_cast(bf16x8, *(const short8*)(brow0 + ks * 32));
        bf16x8 bb1 = __builtin_bit_cast(bf16x8, *(const short8*)(brow1 + ks * 32));
        acc00 = __builtin_amdgcn_mfma_f32_16x16x32_bf16(a0, bb0, acc00, 0, 0, 0);
        acc10 = __builtin_amdgcn_mfma_f32_16x16x32_bf16(a1, bb0, acc10, 0, 0, 0);
        acc01 = __builtin_amdgcn_mfma_f32_16x16x32_bf16(a0, bb1, acc01, 0, 0, 0);
        acc11 = __builtin_amdgcn_mfma_f32_16x16x32_bf16(a1, bb1, acc11, 0, 0, 0);
    }

    // ---- Epilogue: C/D row=(quad*4+reg) -> w, col=l16 -> co-local ----
    #pragma unroll
    for (int j = 0; j < 2; ++j) {
        const int co = (nt0 + j) * 16 + l16;
        const float bv = bias[co];
        float* orow = out + (((size_t)(b * CO_ + co)) * H_ + h) * W_ + w0;
        const f32x4 r0 = j ? acc01 : acc00;
        const f32x4 r1 = j ? acc11 : acc10;
        const int wl0 = quad * 4;
        *(float4*)(orow + wl0)      = make_float4(r0.x + bv, r0.y + bv, r0.z + bv, r0.w + bv);
        *(float4*)(orow + wl0 + 16) = make_float4(r1.x + bv, r1.y + bv, r1.z + bv, r1.w + bv);
    }
}

// ---- fp32 fallback (round-1 kernel, direct W layout) if ws is too small ----
#define WT 16
__global__ __launch_bounds__(256) void sconv_fp32(
    const float* __restrict__ x, const float* __restrict__ Coef,
    const float* __restrict__ Wg, const float* __restrict__ bias,
    float* __restrict__ out)
{
    __shared__ float Cf[81];
    __shared__ float Zl[C_ * 9 * WT];
    const int tid = threadIdx.x;
    const int bx  = blockIdx.x;
    const int wt  = bx & 7;
    const int h   = (bx >> 3) & 127;
    const int b   = bx >> 10;
    const int w0  = wt * WT;
    if (tid < 81) Cf[tid] = Coef[tid];
    __syncthreads();
    for (int task = tid; task < C_ * WT; task += 256) {
        const int c = task >> 4, wl = task & 15, w = w0 + wl;
        const float* xb = x + (b * C_ + c) * H_ * W_;
        float p[9];
        #pragma unroll
        for (int dy = 0; dy < 3; ++dy) {
            const int hy = h + dy - 1; const bool hin = (unsigned)hy < (unsigned)H_;
            #pragma unroll
            for (int dx = 0; dx < 3; ++dx) {
                const int wx = w + dx - 1; const bool win = (unsigned)wx < (unsigned)W_;
                p[dy * 3 + dx] = (hin && win) ? xb[hy * W_ + wx] : 0.0f;
            }
        }
        float v[8];
        #pragma unroll
        for (int ii = 0; ii < 8; ++ii) {
            const int i = ii + (ii >> 2);
            float acc = 0.0f;
            #pragma unroll
            for (int j = 0; j < 9; ++j) acc = fmaf(Cf[i * 9 + j], p[j], acc);
            v[ii] = acc;
        }
        cswap(v[0], v[1]); cswap(v[2], v[3]); cswap(v[4], v[5]); cswap(v[6], v[7]);
        cswap(v[0], v[2]); cswap(v[1], v[3]); cswap(v[4], v[6]); cswap(v[5], v[7]);
        cswap(v[1], v[2]); cswap(v[5], v[6]);
        cswap(v[0], v[4]); cswap(v[1], v[5]); cswap(v[2], v[6]); cswap(v[3], v[7]);
        cswap(v[2], v[4]); cswap(v[3], v[5]);
        cswap(v[1], v[2]); cswap(v[3], v[4]); cswap(v[5], v[6]);
        const int base = c * 9 * WT + wl;
        Zl[base + 0*WT]=v[0]; Zl[base + 1*WT]=v[1]; Zl[base + 2*WT]=v[2]; Zl[base + 3*WT]=v[3];
        Zl[base + 4*WT]=p[4];
        Zl[base + 5*WT]=v[4]; Zl[base + 6*WT]=v[5]; Zl[base + 7*WT]=v[6]; Zl[base + 8*WT]=v[7];
    }
    __syncthreads();
    const int co = tid >> 1, w0l = (tid & 1) * 8;
    float acc[8];
    #pragma unroll
    for (int i = 0; i < 8; ++i) acc[i] = 0.0f;
    for (int c = 0; c < C_; ++c) {
        #pragma unroll
        for (int t = 0; t < 9; ++t) {
            const float wv = Wg[(co * C_ + c) * 9 + t];
            const float* zp = &Zl[(c * 9 + t) * WT + w0l];
            const float4 za = *(const float4*)zp;
            const float4 zb = *(const float4*)(zp + 4);
            acc[0]=fmaf(za.x,wv,acc[0]); acc[1]=fmaf(za.y,wv,acc[1]);
            acc[2]=fmaf(za.z,wv,acc[2]); acc[3]=fmaf(za.w,wv,acc[3]);
            acc[4]=fmaf(zb.x,wv,acc[4]); acc[5]=fmaf(zb.y,wv,acc[5]);
            acc[6]=fmaf(zb.z,wv,acc[6]); acc[7]=fmaf(zb.w,wv,acc[7]);
        }
    }
    const float bv = bias[co];
    float* op = out + ((b * CO_ + co) * H_ + h) * W_ + w0 + w0l;
    *(float4*)(op)     = make_float4(acc[0]+bv, acc[1]+bv, acc[2]+bv, acc[3]+bv);
    *(float4*)(op + 4) = make_float4(acc[4]+bv, acc[5]+bv, acc[6]+bv, acc[7]+bv);
}

extern "C" void kernel_launch(void* const* d_in, const int* in_sizes, int n_in,
                              void* d_out, int out_size, void* d_ws, size_t ws_size,
                              hipStream_t stream) {
    const float* x    = (const float*)d_in[0];
    const float* Coef = (const float*)d_in[1];
    const float* Wg   = (const float*)d_in[2];
    const float* bias = (const float*)d_in[3];
    float* out = (float*)d_out;

    const size_t need = (size_t)CO_ * K_ * sizeof(ushort);   // 147456 B
    if (ws_size >= need) {
        ushort* Wb = (ushort*)d_ws;
        conv_W_bf16<<<(CO_ * K_ + 255) / 256, 256, 0, stream>>>(Wg, Wb);
        sconv_mfma<<<B_ * H_ * 4, 256, 0, stream>>>(x, Coef, Wb, bias, out);
    } else {
        sconv_fp32<<<B_ * H_ * 8, 256, 0, stream>>>(x, Coef, Wg, bias, out);
    }
}

// Round 6
// 176.557 us; speedup vs baseline: 2.3193x; 1.0406x over previous
//
#include <hip/hip_runtime.h>
#include <hip/hip_bf16.h>

// SConv: x(8,64,128,128) f32, Coefficient(9,9), W(128,64,3,3), b(128)
// out[b,co,h,w] = sum_{c,t} z[b,c,h,w][t] * W[co,c,t] + b[co]
// z = [sorted8(y[noncenter])[0:4], center, sorted8[4:8]],
// y_i = sum_j Coefficient[i,j] * patch_j (3x3 neighborhood, zero pad 1).
//
// Round 6 (vs round 5, 121 us):
//  - Phase A processes 2 adjacent w-sites per thread with f32x2 packed math
//    (v_pk_fma_f32 for the matvec; shared patch loads 12 dwords / 2 sites).
//  - Z LDS rows stride 580 elems (1160 B == 8 mod 128): Phase-A writes are
//    2-way (free), no XOR swizzle; stores packed as 4x b32 + 1x b16 per site.
//  - Coefficient read directly from global (uniform addr -> s_load / const
//    cache) instead of 72 ds_read broadcasts per task; drops a barrier.
// Phase B: MFMA 16x16x32 bf16, verified layouts (m89/m91/m97); A-frag via two
// 8B LDS loads (rows 8B-aligned), B-frag b128 from global Wb (B^T layout).

#define B_   8
#define C_   64
#define H_   128
#define W_   128
#define CO_  128
#define K_   576    // C_*9
#define MT   32     // sites (w) per block
#define SROW 580    // LDS row stride in elements (1160 B == 8 mod 128)

typedef __attribute__((ext_vector_type(8))) short  short8;
typedef __attribute__((ext_vector_type(8))) __bf16 bf16x8;
typedef __attribute__((ext_vector_type(4))) float  f32x4;
typedef __attribute__((ext_vector_type(2))) float  f32x2;
typedef __attribute__((ext_vector_type(4))) ushort u16x4;

__device__ __forceinline__ void cswap2(f32x2 &a, f32x2 &b) {
    f32x2 lo = __builtin_elementwise_min(a, b);
    f32x2 hi = __builtin_elementwise_max(a, b);
    a = lo; b = hi;
}

__device__ __forceinline__ ushort f2bf(float f) {
    union { float f; unsigned u; } v; v.f = f;
    unsigned r = v.u + 0x7fffu + ((v.u >> 16) & 1u);  // RNE
    return (ushort)(r >> 16);
}

__device__ __forceinline__ unsigned pack2bf(float lo, float hi) {
    union { __hip_bfloat162 h; unsigned u; } cv;
    cv.h = __float22bfloat162_rn(make_float2(lo, hi));  // x->low word
    return cv.u;
}

__device__ __forceinline__ bf16x8 ldsA(const ushort* p) {  // 16B at 8B align
    union { u16x4 h[2]; bf16x8 v; } u;
    u.h[0] = *(const u16x4*)p;
    u.h[1] = *(const u16x4*)(p + 4);
    return u.v;
}

// W[co][c][t] f32 -> bf16 (layout already B^T = [n=co][k=c*9+t])
__global__ __launch_bounds__(256) void conv_W_bf16(const float* __restrict__ Wg,
                                                   ushort* __restrict__ Wb) {
    int i = blockIdx.x * 256 + threadIdx.x;
    if (i < CO_ * K_) Wb[i] = f2bf(Wg[i]);
}

__global__ __launch_bounds__(256) void sconv_mfma(
    const float* __restrict__ x,
    const float* __restrict__ Coef,
    const ushort* __restrict__ Wb,     // bf16 bits [co][k]
    const float* __restrict__ bias,
    float* __restrict__ out)
{
    __shared__ ushort Zl[MT * SROW];   // 37120 B

    const int tid = threadIdx.x;
    const int bx  = blockIdx.x;
    const int wq  = bx & 3;            // which 32-wide quarter of the row
    const int h   = (bx >> 2) & 127;
    const int b   = bx >> 9;
    const int w0  = wq * MT;

    // ---- Phase A: z for 64 c x 32 sites; 2 sites (pair) per thread ----
    for (int it = 0; it < 4; ++it) {           // 1024 pair-tasks / 256 thr
        const int task = tid + it * 256;
        const int c  = task >> 4;
        const int pi = task & 15;              // site pair index
        const int w  = w0 + pi * 2;
        const float* xb = x + ((size_t)(b * C_ + c)) * (H_ * W_);

        // 3 rows x 4 cols of padded input (covers both sites' 3x3 patches)
        float r[3][4];
        #pragma unroll
        for (int dy = 0; dy < 3; ++dy) {
            const int hy = h + dy - 1;
            const bool hin = (unsigned)hy < (unsigned)H_;
            #pragma unroll
            for (int dx = 0; dx < 4; ++dx) {
                const int wx = w + dx - 1;
                const bool win = (unsigned)wx < (unsigned)W_;
                r[dy][dx] = (hin && win) ? xb[hy * W_ + wx] : 0.0f;
            }
        }

        f32x2 p2[9];
        #pragma unroll
        for (int dy = 0; dy < 3; ++dy)
            #pragma unroll
            for (int dx = 0; dx < 3; ++dx)
                p2[dy * 3 + dx] = (f32x2){ r[dy][dx], r[dy][dx + 1] };

        // y_i for i in {0,1,2,3,5,6,7,8}; Coef via uniform (scalar) loads
        f32x2 v2[8];
        #pragma unroll
        for (int ii = 0; ii < 8; ++ii) {
            const int i = ii + (ii >> 2);
            f32x2 acc = p2[0] * Coef[i * 9];
            #pragma unroll
            for (int j = 1; j < 9; ++j) acc += p2[j] * Coef[i * 9 + j];
            v2[ii] = acc;
        }

        // Batcher odd-even mergesort, 8 elems, ascending (19 comparators)
        cswap2(v2[0],v2[1]); cswap2(v2[2],v2[3]); cswap2(v2[4],v2[5]); cswap2(v2[6],v2[7]);
        cswap2(v2[0],v2[2]); cswap2(v2[1],v2[3]); cswap2(v2[4],v2[6]); cswap2(v2[5],v2[7]);
        cswap2(v2[1],v2[2]); cswap2(v2[5],v2[6]);
        cswap2(v2[0],v2[4]); cswap2(v2[1],v2[5]); cswap2(v2[2],v2[6]); cswap2(v2[3],v2[7]);
        cswap2(v2[2],v2[4]); cswap2(v2[3],v2[5]);
        cswap2(v2[1],v2[2]); cswap2(v2[3],v2[4]); cswap2(v2[5],v2[6]);

        f32x2 z2[9] = { v2[0], v2[1], v2[2], v2[3], p2[4],
                        v2[4], v2[5], v2[6], v2[7] };

        const int k0 = c * 9;
        ushort* zr0 = &Zl[(pi * 2    ) * SROW];
        ushort* zr1 = &Zl[(pi * 2 + 1) * SROW];
        if ((k0 & 1) == 0) {                    // pairs k0.., single at k0+8
            #pragma unroll
            for (int q = 0; q < 4; ++q) {
                *(unsigned*)&zr0[k0 + 2*q] = pack2bf(z2[2*q][0], z2[2*q+1][0]);
                *(unsigned*)&zr1[k0 + 2*q] = pack2bf(z2[2*q][1], z2[2*q+1][1]);
            }
            zr0[k0 + 8] = f2bf(z2[8][0]);
            zr1[k0 + 8] = f2bf(z2[8][1]);
        } else {                                // single at k0, pairs k0+1..
            zr0[k0] = f2bf(z2[0][0]);
            zr1[k0] = f2bf(z2[0][1]);
            #pragma unroll
            for (int q = 0; q < 4; ++q) {
                *(unsigned*)&zr0[k0 + 1 + 2*q] = pack2bf(z2[1+2*q][0], z2[2+2*q][0]);
                *(unsigned*)&zr1[k0 + 1 + 2*q] = pack2bf(z2[1+2*q][1], z2[2+2*q][1]);
            }
        }
    }
    __syncthreads();

    // ---- Phase B: MFMA GEMM  out[m, n=co] = sum_k Z[m,k] * W^T[n,k] ----
    const int wave = tid >> 6;         // 4 waves
    const int lane = tid & 63;
    const int quad = lane >> 4;
    const int l16  = lane & 15;
    const int nt0  = wave * 2;         // n-tiles nt0, nt0+1 (co)

    const ushort* arow0 = &Zl[l16 * SROW];           // m-tile 0 row
    const ushort* arow1 = &Zl[(l16 + 16) * SROW];    // m-tile 1 row
    const ushort* brow0 = Wb + (size_t)(nt0 * 16 + l16) * K_ + quad * 8;
    const ushort* brow1 = brow0 + (size_t)16 * K_;

    f32x4 acc00 = {0.f,0.f,0.f,0.f}, acc01 = acc00, acc10 = acc00, acc11 = acc00;

    #pragma unroll
    for (int ks = 0; ks < 18; ++ks) {
        const int ko = ks * 32 + quad * 8;     // this lane's k-chunk base
        bf16x8 a0  = ldsA(arow0 + ko);
        bf16x8 a1  = ldsA(arow1 + ko);
        bf16x8 bb0 = __builtin_bit_cast(bf16x8, *(const short8*)(brow0 + ks * 32));
        bf16x8 bb1 = __builtin_bit_cast(bf16x8, *(const short8*)(brow1 + ks * 32));
        acc00 = __builtin_amdgcn_mfma_f32_16x16x32_bf16(a0, bb0, acc00, 0, 0, 0);
        acc10 = __builtin_amdgcn_mfma_f32_16x16x32_bf16(a1, bb0, acc10, 0, 0, 0);
        acc01 = __builtin_amdgcn_mfma_f32_16x16x32_bf16(a0, bb1, acc01, 0, 0, 0);
        acc11 = __builtin_amdgcn_mfma_f32_16x16x32_bf16(a1, bb1, acc11, 0, 0, 0);
    }

    // ---- Epilogue: C/D row=(quad*4+reg) -> w, col=l16 -> co-local ----
    #pragma unroll
    for (int j = 0; j < 2; ++j) {
        const int co = (nt0 + j) * 16 + l16;
        const float bv = bias[co];
        float* orow = out + (((size_t)(b * CO_ + co)) * H_ + h) * W_ + w0;
        const f32x4 r0 = j ? acc01 : acc00;
        const f32x4 r1 = j ? acc11 : acc10;
        const int wl0 = quad * 4;
        *(float4*)(orow + wl0)      = make_float4(r0.x + bv, r0.y + bv, r0.z + bv, r0.w + bv);
        *(float4*)(orow + wl0 + 16) = make_float4(r1.x + bv, r1.y + bv, r1.z + bv, r1.w + bv);
    }
}

// ---- fp32 fallback (round-1 kernel, direct W layout) if ws is too small ----
#define WT 16
__device__ __forceinline__ void cswap(float &a, float &b) {
    float lo = fminf(a, b);
    float hi = fmaxf(a, b);
    a = lo; b = hi;
}
__global__ __launch_bounds__(256) void sconv_fp32(
    const float* __restrict__ x, const float* __restrict__ Coef,
    const float* __restrict__ Wg, const float* __restrict__ bias,
    float* __restrict__ out)
{
    __shared__ float Cf[81];
    __shared__ float Zl[C_ * 9 * WT];
    const int tid = threadIdx.x;
    const int bx  = blockIdx.x;
    const int wt  = bx & 7;
    const int h   = (bx >> 3) & 127;
    const int b   = bx >> 10;
    const int w0  = wt * WT;
    if (tid < 81) Cf[tid] = Coef[tid];
    __syncthreads();
    for (int task = tid; task < C_ * WT; task += 256) {
        const int c = task >> 4, wl = task & 15, w = w0 + wl;
        const float* xb = x + (b * C_ + c) * H_ * W_;
        float p[9];
        #pragma unroll
        for (int dy = 0; dy < 3; ++dy) {
            const int hy = h + dy - 1; const bool hin = (unsigned)hy < (unsigned)H_;
            #pragma unroll
            for (int dx = 0; dx < 3; ++dx) {
                const int wx = w + dx - 1; const bool win = (unsigned)wx < (unsigned)W_;
                p[dy * 3 + dx] = (hin && win) ? xb[hy * W_ + wx] : 0.0f;
            }
        }
        float v[8];
        #pragma unroll
        for (int ii = 0; ii < 8; ++ii) {
            const int i = ii + (ii >> 2);
            float acc = 0.0f;
            #pragma unroll
            for (int j = 0; j < 9; ++j) acc = fmaf(Cf[i * 9 + j], p[j], acc);
            v[ii] = acc;
        }
        cswap(v[0], v[1]); cswap(v[2], v[3]); cswap(v[4], v[5]); cswap(v[6], v[7]);
        cswap(v[0], v[2]); cswap(v[1], v[3]); cswap(v[4], v[6]); cswap(v[5], v[7]);
        cswap(v[1], v[2]); cswap(v[5], v[6]);
        cswap(v[0], v[4]); cswap(v[1], v[5]); cswap(v[2], v[6]); cswap(v[3], v[7]);
        cswap(v[2], v[4]); cswap(v[3], v[5]);
        cswap(v[1], v[2]); cswap(v[3], v[4]); cswap(v[5], v[6]);
        const int base = c * 9 * WT + wl;
        Zl[base + 0*WT]=v[0]; Zl[base + 1*WT]=v[1]; Zl[base + 2*WT]=v[2]; Zl[base + 3*WT]=v[3];
        Zl[base + 4*WT]=p[4];
        Zl[base + 5*WT]=v[4]; Zl[base + 6*WT]=v[5]; Zl[base + 7*WT]=v[6]; Zl[base + 8*WT]=v[7];
    }
    __syncthreads();
    const int co = tid >> 1, w0l = (tid & 1) * 8;
    float acc[8];
    #pragma unroll
    for (int i = 0; i < 8; ++i) acc[i] = 0.0f;
    for (int c = 0; c < C_; ++c) {
        #pragma unroll
        for (int t = 0; t < 9; ++t) {
            const float wv = Wg[(co * C_ + c) * 9 + t];
            const float* zp = &Zl[(c * 9 + t) * WT + w0l];
            const float4 za = *(const float4*)zp;
            const float4 zb = *(const float4*)(zp + 4);
            acc[0]=fmaf(za.x,wv,acc[0]); acc[1]=fmaf(za.y,wv,acc[1]);
            acc[2]=fmaf(za.z,wv,acc[2]); acc[3]=fmaf(za.w,wv,acc[3]);
            acc[4]=fmaf(zb.x,wv,acc[4]); acc[5]=fmaf(zb.y,wv,acc[5]);
            acc[6]=fmaf(zb.z,wv,acc[6]); acc[7]=fmaf(zb.w,wv,acc[7]);
        }
    }
    const float bv = bias[co];
    float* op = out + ((b * CO_ + co) * H_ + h) * W_ + w0 + w0l;
    *(float4*)(op)     = make_float4(acc[0]+bv, acc[1]+bv, acc[2]+bv, acc[3]+bv);
    *(float4*)(op + 4) = make_float4(acc[4]+bv, acc[5]+bv, acc[6]+bv, acc[7]+bv);
}

extern "C" void kernel_launch(void* const* d_in, const int* in_sizes, int n_in,
                              void* d_out, int out_size, void* d_ws, size_t ws_size,
                              hipStream_t stream) {
    const float* x    = (const float*)d_in[0];
    const float* Coef = (const float*)d_in[1];
    const float* Wg   = (const float*)d_in[2];
    const float* bias = (const float*)d_in[3];
    float* out = (float*)d_out;

    const size_t need = (size_t)CO_ * K_ * sizeof(ushort);   // 147456 B
    if (ws_size >= need) {
        ushort* Wb = (ushort*)d_ws;
        conv_W_bf16<<<(CO_ * K_ + 255) / 256, 256, 0, stream>>>(Wg, Wb);
        sconv_mfma<<<B_ * H_ * 4, 256, 0, stream>>>(x, Coef, Wb, bias, out);
    } else {
        sconv_fp32<<<B_ * H_ * 8, 256, 0, stream>>>(x, Coef, Wg, bias, out);
    }
}

// Round 7
// 167.330 us; speedup vs baseline: 2.4472x; 1.0551x over previous
//
#include <hip/hip_runtime.h>
#include <hip/hip_bf16.h>

// SConv: x(8,64,128,128) f32, Coefficient(9,9), W(128,64,3,3), b(128)
// out[b,co,h,w] = sum_{c,t} z[b,c,h,w][t] * W[co,c,t] + b[co]
// z = [sorted8(y[noncenter])[0:4], center, sorted8[4:8]],
// y_i = sum_j Coefficient[i,j] * patch_j (3x3 neighborhood, zero pad 1).
//
// Round 7 (vs round 6, 106 us, latency-bound: VALU 29% / MFMA 7% / occ 40%):
//  - 512 threads (8 waves)/block, same 37 KB LDS -> 4 blocks/CU = 32 waves/CU
//    (was 16): doubles latency hiding.
//  - Interior fast path in Phase A: one base pointer + 12 plain dword loads
//    with immediate offsets (no cmp/cndmask chains); slow path only at edges.
//  - Phase B: 1 n-tile per wave (2 m-tiles x 18 ks = 36 MFMAs).
// MFMA 16x16x32 bf16, verified layouts (m89/m91/m97). Z rows stride 580
// (1160 B == 8 mod 128 -> conflict-light), packed b32 stores (parity trick).

#define B_   8
#define C_   64
#define H_   128
#define W_   128
#define CO_  128
#define K_   576    // C_*9
#define MT   32     // sites (w) per block
#define SROW 580    // LDS row stride in elements

typedef __attribute__((ext_vector_type(8))) short  short8;
typedef __attribute__((ext_vector_type(8))) __bf16 bf16x8;
typedef __attribute__((ext_vector_type(4))) float  f32x4;
typedef __attribute__((ext_vector_type(2))) float  f32x2;
typedef __attribute__((ext_vector_type(4))) ushort u16x4;

__device__ __forceinline__ void cswap2(f32x2 &a, f32x2 &b) {
    f32x2 lo = __builtin_elementwise_min(a, b);
    f32x2 hi = __builtin_elementwise_max(a, b);
    a = lo; b = hi;
}

__device__ __forceinline__ ushort f2bf(float f) {
    union { float f; unsigned u; } v; v.f = f;
    unsigned r = v.u + 0x7fffu + ((v.u >> 16) & 1u);  // RNE
    return (ushort)(r >> 16);
}

__device__ __forceinline__ unsigned pack2bf(float lo, float hi) {
    union { __hip_bfloat162 h; unsigned u; } cv;
    cv.h = __float22bfloat162_rn(make_float2(lo, hi));  // x->low word
    return cv.u;
}

__device__ __forceinline__ bf16x8 ldsA(const ushort* p) {  // 16B at 8B align
    union { u16x4 h[2]; bf16x8 v; } u;
    u.h[0] = *(const u16x4*)p;
    u.h[1] = *(const u16x4*)(p + 4);
    return u.v;
}

// W[co][c][t] f32 -> bf16 (layout already B^T = [n=co][k=c*9+t])
__global__ __launch_bounds__(256) void conv_W_bf16(const float* __restrict__ Wg,
                                                   ushort* __restrict__ Wb) {
    int i = blockIdx.x * 256 + threadIdx.x;
    if (i < CO_ * K_) Wb[i] = f2bf(Wg[i]);
}

__global__ __launch_bounds__(512, 8) void sconv_mfma(
    const float* __restrict__ x,
    const float* __restrict__ Coef,
    const ushort* __restrict__ Wb,     // bf16 bits [co][k]
    const float* __restrict__ bias,
    float* __restrict__ out)
{
    __shared__ ushort Zl[MT * SROW];   // 37120 B

    const int tid = threadIdx.x;
    const int bx  = blockIdx.x;
    const int wq  = bx & 3;            // which 32-wide quarter of the row
    const int h   = (bx >> 2) & 127;
    const int b   = bx >> 9;
    const int w0  = wq * MT;

    // ---- Phase A: z for 64 c x 32 sites; 2 adjacent sites per thread ----
    #pragma unroll
    for (int it = 0; it < 2; ++it) {           // 1024 pair-tasks / 512 thr
        const int task = tid + it * 512;
        const int c  = task >> 4;
        const int pi = task & 15;              // site pair index
        const int w  = w0 + pi * 2;
        const float* xb = x + ((size_t)(b * C_ + c)) * (H_ * W_);

        // 3 rows x 4 cols of padded input (covers both sites' 3x3 patches)
        float r[3][4];
        if (h >= 1 && h <= 126 && w >= 1 && w <= 125) {
            const float* bp = xb + (h - 1) * W_ + (w - 1);
            #pragma unroll
            for (int dy = 0; dy < 3; ++dy)
                #pragma unroll
                for (int dx = 0; dx < 4; ++dx)
                    r[dy][dx] = bp[dy * W_ + dx];
        } else {
            #pragma unroll
            for (int dy = 0; dy < 3; ++dy) {
                const int hy = h + dy - 1;
                const bool hin = (unsigned)hy < (unsigned)H_;
                #pragma unroll
                for (int dx = 0; dx < 4; ++dx) {
                    const int wx = w + dx - 1;
                    const bool win = (unsigned)wx < (unsigned)W_;
                    r[dy][dx] = (hin && win) ? xb[hy * W_ + wx] : 0.0f;
                }
            }
        }

        f32x2 p2[9];
        #pragma unroll
        for (int dy = 0; dy < 3; ++dy)
            #pragma unroll
            for (int dx = 0; dx < 3; ++dx)
                p2[dy * 3 + dx] = (f32x2){ r[dy][dx], r[dy][dx + 1] };

        // y_i for i in {0,1,2,3,5,6,7,8}; Coef via uniform (scalar) loads
        f32x2 v2[8];
        #pragma unroll
        for (int ii = 0; ii < 8; ++ii) {
            const int i = ii + (ii >> 2);
            f32x2 acc = p2[0] * Coef[i * 9];
            #pragma unroll
            for (int j = 1; j < 9; ++j) acc += p2[j] * Coef[i * 9 + j];
            v2[ii] = acc;
        }

        // Batcher odd-even mergesort, 8 elems, ascending (19 comparators)
        cswap2(v2[0],v2[1]); cswap2(v2[2],v2[3]); cswap2(v2[4],v2[5]); cswap2(v2[6],v2[7]);
        cswap2(v2[0],v2[2]); cswap2(v2[1],v2[3]); cswap2(v2[4],v2[6]); cswap2(v2[5],v2[7]);
        cswap2(v2[1],v2[2]); cswap2(v2[5],v2[6]);
        cswap2(v2[0],v2[4]); cswap2(v2[1],v2[5]); cswap2(v2[2],v2[6]); cswap2(v2[3],v2[7]);
        cswap2(v2[2],v2[4]); cswap2(v2[3],v2[5]);
        cswap2(v2[1],v2[2]); cswap2(v2[3],v2[4]); cswap2(v2[5],v2[6]);

        f32x2 z2[9] = { v2[0], v2[1], v2[2], v2[3], p2[4],
                        v2[4], v2[5], v2[6], v2[7] };

        const int k0 = c * 9;
        ushort* zr0 = &Zl[(pi * 2    ) * SROW];
        ushort* zr1 = &Zl[(pi * 2 + 1) * SROW];
        if ((k0 & 1) == 0) {                    // pairs k0.., single at k0+8
            #pragma unroll
            for (int q = 0; q < 4; ++q) {
                *(unsigned*)&zr0[k0 + 2*q] = pack2bf(z2[2*q][0], z2[2*q+1][0]);
                *(unsigned*)&zr1[k0 + 2*q] = pack2bf(z2[2*q][1], z2[2*q+1][1]);
            }
            zr0[k0 + 8] = f2bf(z2[8][0]);
            zr1[k0 + 8] = f2bf(z2[8][1]);
        } else {                                // single at k0, pairs k0+1..
            zr0[k0] = f2bf(z2[0][0]);
            zr1[k0] = f2bf(z2[0][1]);
            #pragma unroll
            for (int q = 0; q < 4; ++q) {
                *(unsigned*)&zr0[k0 + 1 + 2*q] = pack2bf(z2[1+2*q][0], z2[2+2*q][0]);
                *(unsigned*)&zr1[k0 + 1 + 2*q] = pack2bf(z2[1+2*q][1], z2[2+2*q][1]);
            }
        }
    }
    __syncthreads();

    // ---- Phase B: MFMA GEMM  out[m, n=co] = sum_k Z[m,k] * W^T[n,k] ----
    const int wave = tid >> 6;         // 8 waves -> n-tile = wave
    const int lane = tid & 63;
    const int quad = lane >> 4;
    const int l16  = lane & 15;

    const ushort* arow0 = &Zl[l16 * SROW];           // m-tile 0 row
    const ushort* arow1 = &Zl[(l16 + 16) * SROW];    // m-tile 1 row
    const ushort* brow  = Wb + (size_t)(wave * 16 + l16) * K_ + quad * 8;

    f32x4 acc0 = {0.f,0.f,0.f,0.f}, acc1 = acc0;

    #pragma unroll
    for (int ks = 0; ks < 18; ++ks) {
        const int ko = ks * 32 + quad * 8;     // this lane's k-chunk base
        bf16x8 a0 = ldsA(arow0 + ko);
        bf16x8 a1 = ldsA(arow1 + ko);
        bf16x8 bb = __builtin_bit_cast(bf16x8, *(const short8*)(brow + ks * 32));
        acc0 = __builtin_amdgcn_mfma_f32_16x16x32_bf16(a0, bb, acc0, 0, 0, 0);
        acc1 = __builtin_amdgcn_mfma_f32_16x16x32_bf16(a1, bb, acc1, 0, 0, 0);
    }

    // ---- Epilogue: C/D row=(quad*4+reg) -> w, col=l16 -> co-local ----
    const int co = wave * 16 + l16;
    const float bv = bias[co];
    float* orow = out + (((size_t)(b * CO_ + co)) * H_ + h) * W_ + w0;
    const int wl0 = quad * 4;
    *(float4*)(orow + wl0)      = make_float4(acc0.x + bv, acc0.y + bv, acc0.z + bv, acc0.w + bv);
    *(float4*)(orow + wl0 + 16) = make_float4(acc1.x + bv, acc1.y + bv, acc1.z + bv, acc1.w + bv);
}

// ---- fp32 fallback (round-1 kernel, direct W layout) if ws is too small ----
#define WT 16
__device__ __forceinline__ void cswap(float &a, float &b) {
    float lo = fminf(a, b);
    float hi = fmaxf(a, b);
    a = lo; b = hi;
}
__global__ __launch_bounds__(256) void sconv_fp32(
    const float* __restrict__ x, const float* __restrict__ Coef,
    const float* __restrict__ Wg, const float* __restrict__ bias,
    float* __restrict__ out)
{
    __shared__ float Cf[81];
    __shared__ float Zl[C_ * 9 * WT];
    const int tid = threadIdx.x;
    const int bx  = blockIdx.x;
    const int wt  = bx & 7;
    const int h   = (bx >> 3) & 127;
    const int b   = bx >> 10;
    const int w0  = wt * WT;
    if (tid < 81) Cf[tid] = Coef[tid];
    __syncthreads();
    for (int task = tid; task < C_ * WT; task += 256) {
        const int c = task >> 4, wl = task & 15, w = w0 + wl;
        const float* xb = x + (b * C_ + c) * H_ * W_;
        float p[9];
        #pragma unroll
        for (int dy = 0; dy < 3; ++dy) {
            const int hy = h + dy - 1; const bool hin = (unsigned)hy < (unsigned)H_;
            #pragma unroll
            for (int dx = 0; dx < 3; ++dx) {
                const int wx = w + dx - 1; const bool win = (unsigned)wx < (unsigned)W_;
                p[dy * 3 + dx] = (hin && win) ? xb[hy * W_ + wx] : 0.0f;
            }
        }
        float v[8];
        #pragma unroll
        for (int ii = 0; ii < 8; ++ii) {
            const int i = ii + (ii >> 2);
            float acc = 0.0f;
            #pragma unroll
            for (int j = 0; j < 9; ++j) acc = fmaf(Cf[i * 9 + j], p[j], acc);
            v[ii] = acc;
        }
        cswap(v[0], v[1]); cswap(v[2], v[3]); cswap(v[4], v[5]); cswap(v[6], v[7]);
        cswap(v[0], v[2]); cswap(v[1], v[3]); cswap(v[4], v[6]); cswap(v[5], v[7]);
        cswap(v[1], v[2]); cswap(v[5], v[6]);
        cswap(v[0], v[4]); cswap(v[1], v[5]); cswap(v[2], v[6]); cswap(v[3], v[7]);
        cswap(v[2], v[4]); cswap(v[3], v[5]);
        cswap(v[1], v[2]); cswap(v[3], v[4]); cswap(v[5], v[6]);
        const int base = c * 9 * WT + wl;
        Zl[base + 0*WT]=v[0]; Zl[base + 1*WT]=v[1]; Zl[base + 2*WT]=v[2]; Zl[base + 3*WT]=v[3];
        Zl[base + 4*WT]=p[4];
        Zl[base + 5*WT]=v[4]; Zl[base + 6*WT]=v[5]; Zl[base + 7*WT]=v[6]; Zl[base + 8*WT]=v[7];
    }
    __syncthreads();
    const int co = tid >> 1, w0l = (tid & 1) * 8;
    float acc[8];
    #pragma unroll
    for (int i = 0; i < 8; ++i) acc[i] = 0.0f;
    for (int c = 0; c < C_; ++c) {
        #pragma unroll
        for (int t = 0; t < 9; ++t) {
            const float wv = Wg[(co * C_ + c) * 9 + t];
            const float* zp = &Zl[(c * 9 + t) * WT + w0l];
            const float4 za = *(const float4*)zp;
            const float4 zb = *(const float4*)(zp + 4);
            acc[0]=fmaf(za.x,wv,acc[0]); acc[1]=fmaf(za.y,wv,acc[1]);
            acc[2]=fmaf(za.z,wv,acc[2]); acc[3]=fmaf(za.w,wv,acc[3]);
            acc[4]=fmaf(zb.x,wv,acc[4]); acc[5]=fmaf(zb.y,wv,acc[5]);
            acc[6]=fmaf(zb.z,wv,acc[6]); acc[7]=fmaf(zb.w,wv,acc[7]);
        }
    }
    const float bv = bias[co];
    float* op = out + ((b * CO_ + co) * H_ + h) * W_ + w0 + w0l;
    *(float4*)(op)     = make_float4(acc[0]+bv, acc[1]+bv, acc[2]+bv, acc[3]+bv);
    *(float4*)(op + 4) = make_float4(acc[4]+bv, acc[5]+bv, acc[6]+bv, acc[7]+bv);
}

extern "C" void kernel_launch(void* const* d_in, const int* in_sizes, int n_in,
                              void* d_out, int out_size, void* d_ws, size_t ws_size,
                              hipStream_t stream) {
    const float* x    = (const float*)d_in[0];
    const float* Coef = (const float*)d_in[1];
    const float* Wg   = (const float*)d_in[2];
    const float* bias = (const float*)d_in[3];
    float* out = (float*)d_out;

    const size_t need = (size_t)CO_ * K_ * sizeof(ushort);   // 147456 B
    if (ws_size >= need) {
        ushort* Wb = (ushort*)d_ws;
        conv_W_bf16<<<(CO_ * K_ + 255) / 256, 256, 0, stream>>>(Wg, Wb);
        sconv_mfma<<<B_ * H_ * 4, 512, 0, stream>>>(x, Coef, Wb, bias, out);
    } else {
        sconv_fp32<<<B_ * H_ * 8, 256, 0, stream>>>(x, Coef, Wg, bias, out);
    }
}